// Round 9
// baseline (355.916 us; speedup 1.0000x reference)
//
#include <hip/hip_runtime.h>

typedef int i32x4  __attribute__((ext_vector_type(4)));
typedef int i32x16 __attribute__((ext_vector_type(16)));

// ---------------- head weight quant ([k=ic*9+tap][oc] fp32, int-valued) ----------------
__global__ __launch_bounds__(256) void quantw_kernel(
    const float* __restrict__ src, float* __restrict__ dst,
    const float* __restrict__ sw, int per_layer_sw, int OC, int ICK, int total)
{
    int i = blockIdx.x * 256 + threadIdx.x;
    if (i >= total) return;
    int per = OC * ICK;
    int l = i / per;
    int rem = i - l * per;
    int oc = rem / ICK;
    int k = rem - oc * ICK;
    float s = sw[per_layer_sw ? l : 0];
    float v = rintf(src[i] / s);
    v = fminf(fmaxf(v, -127.0f), 127.0f);
    dst[l * per + k * OC + oc] = v;
}

// ---------------- i8 weight prepack: dst[(l*9+tap)][lane][j] ----------------
// oc = lane&31 ; ic = 16*(lane>>5) + j  (K=32 = one tap)
__global__ __launch_bounds__(256) void packw_i8_kernel(
    const float* __restrict__ src, signed char* __restrict__ dst,
    const float* __restrict__ sw, int per_layer_sw, int OC_real, int total)
{
    int i = blockIdx.x * 256 + threadIdx.x;
    if (i >= total) return;
    int l   = i / 9216;
    int r   = i - l * 9216;
    int tap = r >> 10;
    int r2  = r & 1023;
    int lane = r2 >> 4;
    int j   = r2 & 15;
    int oc  = lane & 31;
    int ic  = ((lane >> 5) << 4) + j;
    signed char v = 0;
    if (oc < OC_real) {
        float s = sw[per_layer_sw ? l : 0];
        float q = rintf(src[((l * OC_real + oc) * 32 + ic) * 9 + tap] / s);
        q = fminf(fmaxf(q, -127.0f), 127.0f);
        v = (signed char)(int)q;
    }
    dst[i] = v;
}

// ---------------- per-oc weight sums (bias correction for biased activations) ----------------
__global__ __launch_bounds__(256) void wsum_kernel(
    const float* __restrict__ bb_w, const float* __restrict__ bb_sw,
    const float* __restrict__ tr_w, const float* __restrict__ tr_sw,
    float* __restrict__ wsum)
{
    int t = blockIdx.x * 256 + threadIdx.x;
    if (t >= 416) return;
    int l = t >> 5, oc = t & 31;
    float sum = 0.0f;
    if (l < 12) {
        float s = bb_sw[l];
        for (int k = 0; k < 288; ++k) {
            float q = rintf(bb_w[(l * 32 + oc) * 288 + k] / s);
            sum += fminf(fmaxf(q, -127.0f), 127.0f);
        }
    } else if (oc < 12) {
        float s = tr_sw[0];
        for (int k = 0; k < 288; ++k) {
            float q = rintf(tr_w[oc * 288 + k] / s);
            sum += fminf(fmaxf(q, -127.0f), 127.0f);
        }
    }
    wsum[t] = sum;
}

// ---------------- head: fp32 x (NCHW) -> quant -> 3x3 conv -> BIASED u8 codes channel-last ----------------
__global__ __launch_bounds__(256) void head_kernel(
    const float* __restrict__ x, const float* __restrict__ wq,
    const float* __restrict__ bias, const float* __restrict__ sw_ptr,
    const float* __restrict__ s_ptr, unsigned char* __restrict__ out)
{
    __shared__ unsigned char tile[3][10][34];
    const int tid = threadIdx.x;
    const int x0 = blockIdx.x * 32;
    const int y0 = blockIdx.y * 8;
    const int b  = blockIdx.z;
    const float s = s_ptr[0];

    for (int ch = 0; ch < 3; ++ch) {
        const int base = (b * 3 + ch) << 16;
        for (int p = tid; p < 10 * 34; p += 256) {
            int r = p / 34, c = p - r * 34;
            int gy = y0 + r - 1, gx = x0 + c - 1;
            unsigned char v = 0;
            if ((unsigned)gy < 256u && (unsigned)gx < 256u) {
                float xv = x[base + (gy << 8) + gx];
                float q = (s == 1.0f) ? xv : (xv / s);
                q = rintf(q);
                q = fminf(fmaxf(q, 0.0f), 255.0f);
                v = (unsigned char)q;
            }
            tile[ch][r][c] = v;
        }
    }
    __syncthreads();

    const int c = tid & 31, r = tid >> 5;
    float acc[32];
    #pragma unroll
    for (int i = 0; i < 32; ++i) acc[i] = 0.0f;

    #pragma unroll
    for (int ic = 0; ic < 3; ++ic) {
        float a[9];
        #pragma unroll
        for (int dy = 0; dy < 3; ++dy)
            #pragma unroll
            for (int dx = 0; dx < 3; ++dx)
                a[dy * 3 + dx] = (float)tile[ic][r + dy][c + dx];
        #pragma unroll
        for (int t = 0; t < 9; ++t) {
            const float* wrow = wq + (ic * 9 + t) * 32;
            #pragma unroll
            for (int oc = 0; oc < 32; ++oc)
                acc[oc] = fmaf(a[t], wrow[oc], acc[oc]);
        }
    }

    const float alpha = s * sw_ptr[0];
    unsigned int w8[8] = {0,0,0,0,0,0,0,0};
    #pragma unroll
    for (int oc = 0; oc < 32; ++oc) {
        float y = fmaf(alpha, acc[oc], bias[oc]);
        y = fmaxf(y, 0.0f);
        float v = (s == 1.0f) ? y : (y / s);
        v = rintf(v);
        v = fminf(fmaxf(v, 0.0f), 255.0f);
        w8[oc >> 2] |= ((unsigned int)(unsigned char)v) << (8 * (oc & 3));
    }
    uint4* dst = (uint4*)(out + (size_t)((((b << 8) + (y0 + r)) << 8) + (x0 + c)) * 32);
    // store biased codes: code ^ 0x80 == code - 128 (as i8)
    dst[0] = make_uint4(w8[0] ^ 0x80808080u, w8[1] ^ 0x80808080u, w8[2] ^ 0x80808080u, w8[3] ^ 0x80808080u);
    dst[1] = make_uint4(w8[4] ^ 0x80808080u, w8[5] ^ 0x80808080u, w8[6] ^ 0x80808080u, w8[7] ^ 0x80808080u);
}

// ---------------- backbone/tail: implicit-GEMM 3x3 conv via mfma_i32_32x32x32_i8 ----------------
// Activations = biased codes (code-128) channel-last u8. One tap = K=32 = one MFMA.
// LDS tile: 18 rows x 68 16B-chunks (34 px x 2 halves), chunk-index XOR-swizzled (c^=(c>>3)&7).
template<bool FINAL>
__global__ __launch_bounds__(256, 4) void qconv_i8_kernel(
    const unsigned char* __restrict__ in,
    const unsigned char* __restrict__ resid,
    const signed char* __restrict__ Wp,      // [9][64][16] i8 fragments
    const float* __restrict__ bias,
    const float* __restrict__ wsum,          // [32] sum of int weights per oc
    const float* __restrict__ sw_ptr, int sw_idx,
    const float* __restrict__ s_ptr,
    void* __restrict__ out)
{
    __shared__ unsigned char aT[19584];   // 18*68*16
    const int tid = threadIdx.x;
    const int x0 = blockIdx.x << 5;
    const int y0 = blockIdx.y << 4;
    const int b  = blockIdx.z;

    // ---- stage: pure 16B copies of biased codes (no conversion) ----
    #pragma unroll
    for (int it = 0; it < 5; ++it) {
        int ci = tid + it * 256;
        if (ci < 1224) {
            int row = (ci * 241) >> 14;      // ci / 68 (exact for ci<1224)
            int rem = ci - row * 68;
            int xt = rem >> 1, hf = rem & 1;
            int gy = y0 + row - 1, gx = x0 + xt - 1;
            uint4 v = make_uint4(0x80808080u, 0x80808080u, 0x80808080u, 0x80808080u); // biased zero
            if ((unsigned)gy < 256u && (unsigned)gx < 256u) {
                size_t off = (size_t)((((b << 8) + gy) << 8) + gx) * 32 + (hf << 4);
                v = *(const uint4*)(in + off);
                if (FINAL) {
                    uint4 rv = *(const uint4*)(resid + off);
                    unsigned int* vp = (unsigned int*)&v;
                    const unsigned int* rp = (const unsigned int*)&rv;
                    #pragma unroll
                    for (int w = 0; w < 4; ++w) {
                        unsigned int xw = vp[w], yw = rp[w], ow = 0;
                        #pragma unroll
                        for (int bb = 0; bb < 4; ++bb) {
                            int xs = (int)(signed char)(xw >> (8 * bb));
                            int ys = (int)(signed char)(yw >> (8 * bb));
                            int t = xs + ys + 128;           // sat(a+b,0,255)-128, t >= -128 always
                            if (t > 127) t = 127;
                            ow |= ((unsigned int)(t & 255)) << (8 * bb);
                        }
                        vp[w] = ow;
                    }
                }
            }
            int cs = rem ^ ((rem >> 3) & 7);
            *(uint4*)&aT[(row * 68 + cs) << 4] = v;
        }
    }
    __syncthreads();

    const int lane = tid & 63;
    const int wid  = tid >> 6;
    const int px   = lane & 31;
    const int khf  = lane >> 5;     // K-half: bytes 16*khf..16*khf+15 of the 32-ic pixel
    const int py0  = wid << 2;
    const int gx   = x0 + px;

    i32x16 acc[4];
    #pragma unroll
    for (int p = 0; p < 4; ++p)
        #pragma unroll
        for (int i = 0; i < 16; ++i) acc[p][i] = 0;

    #pragma unroll
    for (int dx = 0; dx < 3; ++dx) {
        const int c  = ((px + dx) << 1) + khf;
        const int cs = c ^ ((c >> 3) & 7);
        i32x4 af[6];
        #pragma unroll
        for (int yl = 0; yl < 6; ++yl)
            af[yl] = *(const i32x4*)&aT[((py0 + yl) * 68 + cs) << 4];
        #pragma unroll
        for (int dy = 0; dy < 3; ++dy) {
            i32x4 wf = *(const i32x4*)(Wp + ((((dy * 3 + dx) << 6) + lane) << 4));
            acc[0] = __builtin_amdgcn_mfma_i32_32x32x32_i8(wf, af[dy + 0], acc[0], 0, 0, 0);
            acc[1] = __builtin_amdgcn_mfma_i32_32x32x32_i8(wf, af[dy + 1], acc[1], 0, 0, 0);
            acc[2] = __builtin_amdgcn_mfma_i32_32x32x32_i8(wf, af[dy + 2], acc[2], 0, 0, 0);
            acc[3] = __builtin_amdgcn_mfma_i32_32x32x32_i8(wf, af[dy + 3], acc[3], 0, 0, 0);
        }
    }

    // ---- epilogue: D col = lane&31 = px ; row r -> oc = (r&3) + 8*(r>>2) + 4*khf ----
    const float s = s_ptr[0];
    const float alpha = s * sw_ptr[sw_idx];

    if (!FINAL) {
        float bv[16];
        #pragma unroll
        for (int r = 0; r < 16; ++r) {
            const int oc = (r & 3) + ((r >> 2) << 3) + (khf << 2);
            bv[r] = fmaf(alpha * 128.0f, wsum[oc], bias[oc]);   // + alpha*128*sum(w)
        }
        #pragma unroll
        for (int py = 0; py < 4; ++py) {
            const int gy = y0 + py0 + py;
            unsigned char* pout = (unsigned char*)out + (((size_t)((((b << 8) + gy) << 8) + gx)) << 5);
            #pragma unroll
            for (int q = 0; q < 4; ++q) {
                unsigned int wv = 0;
                #pragma unroll
                for (int j = 0; j < 4; ++j) {
                    float y = fmaf(alpha, (float)acc[py][4 * q + j], bv[4 * q + j]);
                    y = fmaxf(y, 0.0f);
                    float v = (s == 1.0f) ? y : (y / s);
                    v = rintf(v);
                    v = fminf(fmaxf(v, 0.0f), 255.0f);
                    wv |= ((unsigned int)v) << (8 * j);
                }
                *(unsigned int*)(pout + 8 * q + 4 * khf) = wv ^ 0x80808080u;  // store biased
            }
        }
    } else {
        #pragma unroll
        for (int py = 0; py < 4; ++py) {
            const int gy = y0 + py0 + py;
            #pragma unroll
            for (int r = 0; r < 16; ++r) {
                const int oc = (r & 3) + ((r >> 2) << 3) + (khf << 2);
                if (oc < 12) {
                    float y = fmaf(alpha, (float)acc[py][r],
                                   fmaf(alpha * 128.0f, wsum[oc], bias[oc]));
                    y = fmaxf(y, 0.0f);
                    float v = (s == 1.0f) ? y : (y / s);
                    v = rintf(v);
                    v = fminf(fmaxf(v, 0.0f), 255.0f);
                    float o = (s == 1.0f) ? v : fminf(fmaxf(s * v, 0.0f), 255.0f);
                    const int cc = oc >> 2, r1 = (oc >> 1) & 1, r2 = oc & 1;
                    ((float*)out)[(size_t)(((b * 3 + cc) << 9) + (gy << 1) + r1) * 512 + (gx << 1) + r2] = o;
                }
            }
        }
    }
}

extern "C" void kernel_launch(void* const* d_in, const int* in_sizes, int n_in,
                              void* d_out, int out_size, void* d_ws, size_t ws_size,
                              hipStream_t stream) {
    const float* x       = (const float*)d_in[0];
    const float* head_w  = (const float*)d_in[1];
    const float* head_b  = (const float*)d_in[2];
    const float* head_sw = (const float*)d_in[3];
    const float* bb_w    = (const float*)d_in[4];
    const float* bb_b    = (const float*)d_in[5];
    const float* bb_sw   = (const float*)d_in[6];
    const float* tr_w    = (const float*)d_in[7];
    const float* tr_b    = (const float*)d_in[8];
    const float* tr_sw   = (const float*)d_in[9];
    const float* act_s   = (const float*)d_in[10];

    char* ws = (char*)d_ws;
    unsigned char* buf0 = (unsigned char*)ws;            // y0 biased codes, channel-last u8
    unsigned char* buf1 = buf0 + 16777216;
    unsigned char* buf2 = buf1 + 16777216;
    float* wqH = (float*)(ws + 50331648);                        // [27][32] fp32
    signed char* WpB = (signed char*)(ws + 50331648 + 4096);     // 12 x [9][64][16] i8
    signed char* WpT = WpB + 110592;                             // [9][64][16] i8
    float* wsum = (float*)(ws + 50331648 + 4096 + 110592 + 9216); // [13][32]

    quantw_kernel<<<(864 + 255) / 256, 256, 0, stream>>>(head_w, wqH, head_sw, 0, 32, 27, 864);
    packw_i8_kernel<<<(110592 + 255) / 256, 256, 0, stream>>>(bb_w, WpB, bb_sw, 1, 32, 110592);
    packw_i8_kernel<<<(9216 + 255) / 256, 256, 0, stream>>>(tr_w, WpT, tr_sw, 0, 12, 9216);
    wsum_kernel<<<2, 256, 0, stream>>>(bb_w, bb_sw, tr_w, tr_sw, wsum);

    // head
    head_kernel<<<dim3(8, 32, 8), 256, 0, stream>>>(x, wqH, head_b, head_sw, act_s, buf0);

    // backbone: 12 i8-MFMA layers, ping-pong buf1/buf2 (buf0 preserved for residual)
    dim3 gridB(8, 16, 8);
    const unsigned char* cur = buf0;
    unsigned char* nxt = buf1;
    for (int l = 0; l < 12; ++l) {
        qconv_i8_kernel<false><<<gridB, 256, 0, stream>>>(
            cur, nullptr, WpB + l * 9216, bb_b + l * 32, wsum + l * 32, bb_sw, l, act_s, (void*)nxt);
        cur = nxt;
        nxt = (nxt == buf1) ? buf2 : buf1;
    }

    // tail: input = sat-residual(cur, buf0), conv 32->12, pixel-shuffle fp32 out
    qconv_i8_kernel<true><<<gridB, 256, 0, stream>>>(
        cur, buf0, WpT, tr_b, wsum + 384, tr_sw, 0, act_s, d_out);
}